// Round 3
// baseline (153.535 us; speedup 1.0000x reference)
//
#include <hip/hip_runtime.h>

#define EMBED 768
#define HEADS 12
#define HD 64
#define SEQ 1024
#define BS 8
#define NROWS (BS * HEADS * SEQ) /* 98304 head-view rows, 64 wide */
#define XP 72                    /* padded LDS row (f16 elems) for qkv staging */
#define PLP 40                   /* P-tile stride: 80B rows -> 16B-aligned, quad conflicts 2-way (free) */

typedef _Float16 f16;
typedef f16 f16x4 __attribute__((ext_vector_type(4)));
typedef f16 f16x8 __attribute__((ext_vector_type(8)));
typedef float f32x4 __attribute__((ext_vector_type(4)));

typedef const __attribute__((address_space(1))) unsigned int gu32;
typedef __attribute__((address_space(3))) unsigned int lu32;

// ---------------- Kernel 1: LayerNorm statistics (mu, rstd per 768-row) ----------------
__global__ __launch_bounds__(256) void k_lnstats(const float* __restrict__ x,
                                                 float* __restrict__ mu_out,
                                                 float* __restrict__ rs_out) {
    const int w = threadIdx.x >> 6;
    const int lane = threadIdx.x & 63;
    const int row = blockIdx.x * 4 + w; // 0..8191
    const float4* xr = (const float4*)(x + (long)row * EMBED);
    float s = 0.f, sq = 0.f;
#pragma unroll
    for (int kk = 0; kk < 3; ++kk) {
        float4 v = xr[lane + kk * 64];
        s += v.x + v.y + v.z + v.w;
        sq += v.x * v.x + v.y * v.y + v.z * v.z + v.w * v.w;
    }
#pragma unroll
    for (int off = 32; off; off >>= 1) {
        s += __shfl_xor(s, off, 64);
        sq += __shfl_xor(sq, off, 64);
    }
    if (lane == 0) {
        float mu = s * (1.f / EMBED);
        float var = sq * (1.f / EMBED) - mu * mu;
        mu_out[row] = mu;
        rs_out[row] = rsqrtf(var + 1e-5f);
    }
}

// ------- Kernel 2: fused LN-apply + Q/K/V projection -------
// Q -> row-major [row][64].
// K,V -> MFMA-fragment-interleaved: per head, per 32-kv-row tile, 4 chunks of 512 f16;
//        element offset inside chunk = lane*8 so k_attn tiles are linear 4KB blobs.
__global__ __launch_bounds__(256) void k_qkv(
    const float* __restrict__ x, const float* __restrict__ lw, const float* __restrict__ lb,
    const float* __restrict__ Wq, const float* __restrict__ bq,
    const float* __restrict__ Wk, const float* __restrict__ bk,
    const float* __restrict__ Wv, const float* __restrict__ bv,
    const float* __restrict__ mu, const float* __restrict__ rs,
    f16* __restrict__ qo, f16* __restrict__ ko, f16* __restrict__ vo) {
    __shared__ __align__(16) f16 xh[64 * XP]; // input tile; reused as output staging
    __shared__ __align__(16) f16 wl[3][64 * XP];
    const int t = threadIdx.x;
    const unsigned r0 = (unsigned)blockIdx.x * 64; // global head-view row base
    const int bh = (int)(r0 >> 10);
    const int seq0 = (int)(r0 & 1023);

    // stage the three 64x64 weight matrices (fp32 -> fp16) into LDS, b64 writes
    const float* Ws[3] = {Wq, Wk, Wv};
#pragma unroll
    for (int m = 0; m < 3; ++m) {
        const int base = t * 16;
        const int row = base >> 6, col = base & 63;
        const float4* src = (const float4*)(Ws[m] + base);
        f16* dst = &wl[m][row * XP + col];
#pragma unroll
        for (int j = 0; j < 4; ++j) {
            float4 vv = src[j];
            f16x4 h = {(f16)vv.x, (f16)vv.y, (f16)vv.z, (f16)vv.w};
            *(f16x4*)(dst + j * 4) = h;
        }
    }
    // stage 64 head-view rows of LN(x) into LDS (fp16), b64 writes
    {
        const unsigned fb = r0 * 64u + (unsigned)t * 16u; // < 2^23, 32-bit magic div
        const unsigned xrow = fb / EMBED;
        const unsigned c0 = fb % EMBED;
        const float m_ = mu[xrow], s_ = rs[xrow];
        const int lrow = (t * 16) >> 6, lcol = (t * 16) & 63;
        f16* dst = &xh[lrow * XP + lcol];
        const float4* xp = (const float4*)(x + fb);
        const float4* wp = (const float4*)(lw + c0);
        const float4* bp = (const float4*)(lb + c0);
#pragma unroll
        for (int j = 0; j < 4; ++j) {
            float4 xv = xp[j], wv = wp[j], bv2 = bp[j];
            f16x4 h = {(f16)((xv.x - m_) * s_ * wv.x + bv2.x), (f16)((xv.y - m_) * s_ * wv.y + bv2.y),
                       (f16)((xv.z - m_) * s_ * wv.z + bv2.z), (f16)((xv.w - m_) * s_ * wv.w + bv2.w)};
            *(f16x4*)(dst + j * 4) = h;
        }
    }
    __syncthreads();

    const int lane = t & 63, w = t >> 6, l16 = lane & 15, quad = lane >> 4;
    // A fragments into registers (xh is free for reuse after the next barrier)
    f16x8 a0 = *(const f16x8*)&xh[(w * 16 + l16) * XP + quad * 8];
    f16x8 a1 = *(const f16x8*)&xh[(w * 16 + l16) * XP + 32 + quad * 8];
    const float* Bs[3] = {bq, bk, bv};
    f32x4 acc[3][4];
#pragma unroll
    for (int m = 0; m < 3; ++m) {
#pragma unroll
        for (int nt = 0; nt < 4; ++nt) {
            f16x8 b0 = *(const f16x8*)&wl[m][(nt * 16 + l16) * XP + quad * 8];
            f16x8 b1 = *(const f16x8*)&wl[m][(nt * 16 + l16) * XP + 32 + quad * 8];
            f32x4 a = {0.f, 0.f, 0.f, 0.f};
            a = __builtin_amdgcn_mfma_f32_16x16x32_f16(a0, b0, a, 0, 0, 0);
            a = __builtin_amdgcn_mfma_f32_16x16x32_f16(a1, b1, a, 0, 0, 0);
            const float bias = Bs[m][nt * 16 + l16];
#pragma unroll
            for (int rg = 0; rg < 4; ++rg) a[rg] += bias;
            acc[m][nt] = a;
        }
    }

#pragma unroll
    for (int m = 0; m < 3; ++m) {
        __syncthreads(); // previous users of xh done
        if (m < 2) {
            // stage [row(seq-local)][col(d)] (scalar b16: 4 rows share a col)
#pragma unroll
            for (int nt = 0; nt < 4; ++nt)
#pragma unroll
                for (int rg = 0; rg < 4; ++rg)
                    xh[(w * 16 + quad * 4 + rg) * XP + nt * 16 + l16] = (f16)acc[m][nt][rg];
        } else {
            // stage transposed [col(d)][row(seq-local)] — rg contiguous -> b64
#pragma unroll
            for (int nt = 0; nt < 4; ++nt) {
                f16x4 h = {(f16)acc[m][nt][0], (f16)acc[m][nt][1], (f16)acc[m][nt][2], (f16)acc[m][nt][3]};
                *(f16x4*)&xh[(nt * 16 + l16) * XP + w * 16 + quad * 4] = h;
            }
        }
        __syncthreads();
        if (m == 0) {
            // Q: row-major
#pragma unroll
            for (int c = t; c < 512; c += 256) {
                const int row = c >> 3, c8 = (c & 7) * 8;
                *(f16x8*)(qo + ((long)r0 + row) * 64 + c8) = *(const f16x8*)&xh[row * XP + c8];
            }
        } else if (m == 1) {
            // K: fragment-interleaved. xh[row][c8..c8+7] = K[seq0+row][c8..c8+7]
#pragma unroll
            for (int c = t; c < 512; c += 256) {
                const int row = c >> 3, c8 = (c & 7) * 8;
                const int seq = seq0 + row;
                const int tile = seq >> 5;
                const int l16s = seq & 15, r16 = (seq >> 4) & 1;
                const int cseg = c8 >> 5, qd = (c8 >> 3) & 3;
                const long dst = ((long)bh << 16) + tile * 2048 + (r16 * 2 + cseg) * 512 + qd * 128 + l16s * 8;
                *(f16x8*)(ko + dst) = *(const f16x8*)&xh[row * XP + c8];
            }
        } else {
            // V: fragment-interleaved from transposed staging. xh[d][s8..s8+7] = V[seq0+s8+j][d]
#pragma unroll
            for (int c = t; c < 512; c += 256) {
                const int d = c >> 3, s8 = (c & 7) * 8;
                const int seq = seq0 + s8;
                const int tile = seq >> 5;
                const int qd = (seq & 31) >> 3;
                const int nt = d >> 4, l16d = d & 15;
                const long dst = ((long)bh << 16) + tile * 2048 + nt * 512 + qd * 128 + l16d * 8;
                *(f16x8*)(vo + dst) = *(const f16x8*)&xh[d * XP + s8];
            }
        }
    }
}

// ------- Kernel 3: flash attention, LDS-shared double-buffered K/V -------
// 4 waves share each 8KB K/V tile via global_load_lds (4x traffic cut vs per-wave reads).
// grid = (bh=96, qtile=8): same-bh blocks land on the same XCD (96 % 8 == 0).
__global__ __launch_bounds__(256) void k_attn(const f16* __restrict__ q,
                                              const f16* __restrict__ k,
                                              const f16* __restrict__ vt,
                                              float* __restrict__ out) {
    __shared__ __align__(16) f16 kv[2][2][2048]; // [buf][K/V][4KB tile, fragment-linear]
    __shared__ __align__(16) f16 pl[4][32 * PLP];
    const int t = threadIdx.x;
    const int w = t >> 6, lane = t & 63, l16 = lane & 15, quad = lane >> 4;
    const int bh = blockIdx.x;
    const int q0 = blockIdx.y * 128 + w * 32; // this wave's 32 q-rows
    const long hb = (long)bh * SEQ;
    const f16* kg = k + ((long)bh << 16);
    const f16* vg = vt + ((long)bh << 16);

    // wave w stages chunks {2w, 2w+1} of the 8KB tile (c<4: K chunk c; c>=4: V chunk c-4)
    auto stage = [&](int kt, int buf) {
#pragma unroll
        for (int j = 0; j < 2; ++j) {
            const int c = w * 2 + j;
            const f16* src = ((c < 4) ? kg : vg) + (long)kt * 2048 + (c & 3) * 512 + lane * 8;
            f16* dst = &kv[buf][c >> 2][(c & 3) * 512]; // wave-uniform; HW adds lane*16B
            __builtin_amdgcn_global_load_lds((gu32*)(const void*)src, (lu32*)(void*)dst, 16, 0, 0);
        }
    };

    stage(0, 0); // tile 0 in flight while we set up

    f16x8 qf[2][2];
#pragma unroll
    for (int mt = 0; mt < 2; ++mt) {
        const f16* qp = q + (hb + q0 + mt * 16 + l16) * 64 + quad * 8;
        qf[mt][0] = *(const f16x8*)qp;
        qf[mt][1] = *(const f16x8*)(qp + 32);
    }
    f32x4 o[2][4];
    f32x4 ls[2];
#pragma unroll
    for (int mt = 0; mt < 2; ++mt) {
        ls[mt] = (f32x4){0.f, 0.f, 0.f, 0.f};
#pragma unroll
        for (int nt = 0; nt < 4; ++nt) o[mt][nt] = (f32x4){0.f, 0.f, 0.f, 0.f};
    }
    f16x8 one;
#pragma unroll
    for (int j = 0; j < 8; ++j) one[j] = (f16)1.0f;

    auto body = [&](int buf) {
        f16x8 kf[4], vf[4];
#pragma unroll
        for (int c = 0; c < 4; ++c) {
            kf[c] = *(const f16x8*)&kv[buf][0][c * 512 + lane * 8];
            vf[c] = *(const f16x8*)&kv[buf][1][c * 512 + lane * 8];
        }
        f32x4 s[2][2];
#pragma unroll
        for (int mt = 0; mt < 2; ++mt) {
            f32x4 a = {0.f, 0.f, 0.f, 0.f};
            a = __builtin_amdgcn_mfma_f32_16x16x32_f16(qf[mt][0], kf[0], a, 0, 0, 0);
            a = __builtin_amdgcn_mfma_f32_16x16x32_f16(qf[mt][1], kf[1], a, 0, 0, 0);
            s[mt][0] = a;
            f32x4 b = {0.f, 0.f, 0.f, 0.f};
            b = __builtin_amdgcn_mfma_f32_16x16x32_f16(qf[mt][0], kf[2], b, 0, 0, 0);
            b = __builtin_amdgcn_mfma_f32_16x16x32_f16(qf[mt][1], kf[3], b, 0, 0, 0);
            s[mt][1] = b;
        }
        // fixed-offset exp (no max tracking); offset cancels in final normalization
#pragma unroll
        for (int mt = 0; mt < 2; ++mt)
#pragma unroll
            for (int ct = 0; ct < 2; ++ct)
#pragma unroll
                for (int rg = 0; rg < 4; ++rg) {
                    float p = __expf(s[mt][ct][rg] - 14.f);
                    pl[w][(mt * 16 + quad * 4 + rg) * PLP + ct * 16 + l16] = (f16)p;
                }
        f16x8 pf0 = *(const f16x8*)&pl[w][l16 * PLP + quad * 8];
        f16x8 pf1 = *(const f16x8*)&pl[w][(16 + l16) * PLP + quad * 8];
        ls[0] = __builtin_amdgcn_mfma_f32_16x16x32_f16(pf0, one, ls[0], 0, 0, 0);
        ls[1] = __builtin_amdgcn_mfma_f32_16x16x32_f16(pf1, one, ls[1], 0, 0, 0);
#pragma unroll
        for (int nt = 0; nt < 4; ++nt) {
            o[0][nt] = __builtin_amdgcn_mfma_f32_16x16x32_f16(pf0, vf[nt], o[0][nt], 0, 0, 0);
            o[1][nt] = __builtin_amdgcn_mfma_f32_16x16x32_f16(pf1, vf[nt], o[1][nt], 0, 0, 0);
        }
    };

    __syncthreads(); // tile 0 landed (implicit vmcnt drain)
    int buf = 0;
    for (int kt = 0; kt < SEQ / 32; ++kt) {
        if (kt + 1 < SEQ / 32) stage(kt + 1, buf ^ 1); // async into other buffer
        body(buf);
        __syncthreads(); // drains prefetch; all waves done reading buf
        buf ^= 1;
    }

    // epilogue: normalize by row-sum (ones-MFMA gave exact sums), then /sqrt(64)
#pragma unroll
    for (int mt = 0; mt < 2; ++mt) {
        float inv[4];
#pragma unroll
        for (int rg = 0; rg < 4; ++rg) inv[rg] = 1.f / (ls[mt][rg] * 8.0f);
#pragma unroll
        for (int nt = 0; nt < 4; ++nt) {
            float* op = out + (hb + q0 + mt * 16 + quad * 4) * 64 + nt * 16 + l16;
#pragma unroll
            for (int rg = 0; rg < 4; ++rg) op[(long)rg * 64] = o[mt][nt][rg] * inv[rg];
        }
    }
}

extern "C" void kernel_launch(void* const* d_in, const int* in_sizes, int n_in,
                              void* d_out, int out_size, void* d_ws, size_t ws_size,
                              hipStream_t stream) {
    const float* x = (const float*)d_in[0];
    const float* lw = (const float*)d_in[1];
    const float* lb = (const float*)d_in[2];
    const float* Wq = (const float*)d_in[3];
    const float* bq = (const float*)d_in[4];
    const float* Wk = (const float*)d_in[5];
    const float* bk = (const float*)d_in[6];
    const float* Wv = (const float*)d_in[7];
    const float* bv = (const float*)d_in[8];
    float* out = (float*)d_out;

    char* ws = (char*)d_ws;
    float* mu = (float*)ws;           // 8192 f32
    float* rs = (float*)(ws + 32768); // 8192 f32
    f16* qo = (f16*)(ws + 65536);     // [row][64]
    f16* ko = qo + (long)NROWS * 64;  // fragment-interleaved per head
    f16* vo = ko + (long)NROWS * 64;  // fragment-interleaved per head

    k_lnstats<<<2048, 256, 0, stream>>>(x, mu, rs);
    k_qkv<<<NROWS / 64, 256, 0, stream>>>(x, lw, lb, Wq, bq, Wk, bk, Wv, bv, mu, rs, qo, ko, vo);
    k_attn<<<dim3(BS * HEADS, SEQ / 128), 256, 0, stream>>>(qo, ko, vo, out);
}

// Round 4
// 143.992 us; speedup vs baseline: 1.0663x; 1.0663x over previous
//
#include <hip/hip_runtime.h>

#define EMBED 768
#define HEADS 12
#define HD 64
#define SEQ 1024
#define BS 8
#define NROWS (BS * HEADS * SEQ) /* 98304 head-view rows, 64 wide */
#define XP 72                    /* padded LDS row (f16 elems) for qkv staging */
#define PLP 40                   /* P-tile stride: 80B rows -> 16B-aligned, quad conflicts 2-way (free) */

typedef _Float16 f16;
typedef f16 f16x4 __attribute__((ext_vector_type(4)));
typedef f16 f16x8 __attribute__((ext_vector_type(8)));
typedef float f32x4 __attribute__((ext_vector_type(4)));

// ---------------- Kernel 1: LayerNorm statistics + one-time W->f16 fragment conversion ----------------
// Blocks 0..2047: per-row mu/rstd. Blocks 0..2: additionally convert Wq/Wk/Wv (64x64 f32)
// into MFMA-B-fragment order f16: wf[m*4096 + (nt*2+half)*512 + lane*8 + j]
//   = W[nt*16 + (lane&15)][half*32 + (lane>>4)*8 + j]
__global__ __launch_bounds__(256) void k_lnstats(const float* __restrict__ x,
                                                 const float* __restrict__ Wq,
                                                 const float* __restrict__ Wk,
                                                 const float* __restrict__ Wv,
                                                 float* __restrict__ mu_out,
                                                 float* __restrict__ rs_out,
                                                 f16* __restrict__ wf) {
    const int w = threadIdx.x >> 6;
    const int lane = threadIdx.x & 63;
    const int row = blockIdx.x * 4 + w; // 0..8191
    const float4* xr = (const float4*)(x + (long)row * EMBED);
    float s = 0.f, sq = 0.f;
#pragma unroll
    for (int kk = 0; kk < 3; ++kk) {
        float4 v = xr[lane + kk * 64];
        s += v.x + v.y + v.z + v.w;
        sq += v.x * v.x + v.y * v.y + v.z * v.z + v.w * v.w;
    }
#pragma unroll
    for (int off = 32; off; off >>= 1) {
        s += __shfl_xor(s, off, 64);
        sq += __shfl_xor(sq, off, 64);
    }
    if (lane == 0) {
        float mu = s * (1.f / EMBED);
        float var = sq * (1.f / EMBED) - mu * mu;
        mu_out[row] = mu;
        rs_out[row] = rsqrtf(var + 1e-5f);
    }
    if (blockIdx.x < 3) {
        const float* W = (blockIdx.x == 0) ? Wq : (blockIdx.x == 1) ? Wk : Wv;
        f16* dst = wf + (long)blockIdx.x * 4096;
        const int t = threadIdx.x;
#pragma unroll
        for (int i = 0; i < 2; ++i) {
            const int o = t * 2 + i; // octet index 0..511
            const int nt = o >> 7, half = (o >> 6) & 1, lp = o & 63;
            const int qd = lp >> 4, l16 = lp & 15;
            const float* src = W + (nt * 16 + l16) * 64 + half * 32 + qd * 8;
            float4 v0 = *(const float4*)src, v1 = *(const float4*)(src + 4);
            f16x8 h = {(f16)v0.x, (f16)v0.y, (f16)v0.z, (f16)v0.w,
                       (f16)v1.x, (f16)v1.y, (f16)v1.z, (f16)v1.w};
            *(f16x8*)(dst + o * 8) = h;
        }
    }
}

// ------- Kernel 2: fused LN-apply + Q/K/V projection (weights pre-fragmented in wf) -------
// Q -> row-major [row][64].
// K,V -> MFMA-fragment-interleaved: per head, per 32-kv-row tile, 4 chunks of 512 f16;
//        element offset inside chunk = lane*8 so k_attn loads are lane-contiguous 1KB accesses.
__global__ __launch_bounds__(256) void k_qkv(
    const float* __restrict__ x, const float* __restrict__ lw, const float* __restrict__ lb,
    const f16* __restrict__ wf,
    const float* __restrict__ bq, const float* __restrict__ bk, const float* __restrict__ bv,
    const float* __restrict__ mu, const float* __restrict__ rs,
    f16* __restrict__ qo, f16* __restrict__ ko, f16* __restrict__ vo) {
    __shared__ __align__(16) f16 xh[64 * XP]; // input tile; reused as output staging
    const int t = threadIdx.x;
    const unsigned r0 = (unsigned)blockIdx.x * 64; // global head-view row base
    const int bh = (int)(r0 >> 10);
    const int seq0 = (int)(r0 & 1023);

    // stage 64 head-view rows of LN(x) into LDS (fp16), b64 writes
    {
        const unsigned fb = r0 * 64u + (unsigned)t * 16u; // < 2^23, 32-bit div ok
        const unsigned xrow = fb / EMBED;
        const unsigned c0 = fb % EMBED;
        const float m_ = mu[xrow], s_ = rs[xrow];
        const int lrow = (t * 16) >> 6, lcol = (t * 16) & 63;
        f16* dst = &xh[lrow * XP + lcol];
        const float4* xp = (const float4*)(x + fb);
        const float4* wp = (const float4*)(lw + c0);
        const float4* bp = (const float4*)(lb + c0);
#pragma unroll
        for (int j = 0; j < 4; ++j) {
            float4 xv = xp[j], wv = wp[j], bv2 = bp[j];
            f16x4 h = {(f16)((xv.x - m_) * s_ * wv.x + bv2.x), (f16)((xv.y - m_) * s_ * wv.y + bv2.y),
                       (f16)((xv.z - m_) * s_ * wv.z + bv2.z), (f16)((xv.w - m_) * s_ * wv.w + bv2.w)};
            *(f16x4*)(dst + j * 4) = h;
        }
    }
    __syncthreads();

    const int lane = t & 63, w = t >> 6, l16 = lane & 15, quad = lane >> 4;
    // A fragments into registers (xh is free for reuse after the next barrier)
    f16x8 a0 = *(const f16x8*)&xh[(w * 16 + l16) * XP + quad * 8];
    f16x8 a1 = *(const f16x8*)&xh[(w * 16 + l16) * XP + 32 + quad * 8];
    const float* Bs[3] = {bq, bk, bv};

#pragma unroll
    for (int m = 0; m < 3; ++m) {
        // B-fragments straight from global (L1-hot 24KB working set), no LDS staging
        const f16* wfm = wf + (long)m * 4096 + lane * 8;
        f32x4 acc[4];
#pragma unroll
        for (int nt = 0; nt < 4; ++nt) {
            f16x8 b0 = *(const f16x8*)(wfm + (nt * 2 + 0) * 512);
            f16x8 b1 = *(const f16x8*)(wfm + (nt * 2 + 1) * 512);
            f32x4 a = {0.f, 0.f, 0.f, 0.f};
            a = __builtin_amdgcn_mfma_f32_16x16x32_f16(a0, b0, a, 0, 0, 0);
            a = __builtin_amdgcn_mfma_f32_16x16x32_f16(a1, b1, a, 0, 0, 0);
            const float bias = Bs[m][nt * 16 + l16];
#pragma unroll
            for (int rg = 0; rg < 4; ++rg) a[rg] += bias;
            acc[nt] = a;
        }

        __syncthreads(); // previous users of xh done
        if (m < 2) {
            // stage [row(seq-local)][col(d)] (scalar b16: 4 rows share a col)
#pragma unroll
            for (int nt = 0; nt < 4; ++nt)
#pragma unroll
                for (int rg = 0; rg < 4; ++rg)
                    xh[(w * 16 + quad * 4 + rg) * XP + nt * 16 + l16] = (f16)acc[nt][rg];
        } else {
            // stage transposed [col(d)][row(seq-local)] — rg contiguous -> b64
#pragma unroll
            for (int nt = 0; nt < 4; ++nt) {
                f16x4 h = {(f16)acc[nt][0], (f16)acc[nt][1], (f16)acc[nt][2], (f16)acc[nt][3]};
                *(f16x4*)&xh[(nt * 16 + l16) * XP + w * 16 + quad * 4] = h;
            }
        }
        __syncthreads();
        if (m == 0) {
            // Q: row-major
#pragma unroll
            for (int c = t; c < 512; c += 256) {
                const int row = c >> 3, c8 = (c & 7) * 8;
                *(f16x8*)(qo + ((long)r0 + row) * 64 + c8) = *(const f16x8*)&xh[row * XP + c8];
            }
        } else if (m == 1) {
            // K: fragment-interleaved. xh[row][c8..c8+7] = K[seq0+row][c8..c8+7]
#pragma unroll
            for (int c = t; c < 512; c += 256) {
                const int row = c >> 3, c8 = (c & 7) * 8;
                const int seq = seq0 + row;
                const int tile = seq >> 5;
                const int l16s = seq & 15, r16 = (seq >> 4) & 1;
                const int cseg = c8 >> 5, qd = (c8 >> 3) & 3;
                const long dst = ((long)bh << 16) + tile * 2048 + (r16 * 2 + cseg) * 512 + qd * 128 + l16s * 8;
                *(f16x8*)(ko + dst) = *(const f16x8*)&xh[row * XP + c8];
            }
        } else {
            // V: fragment-interleaved from transposed staging. xh[d][s8..s8+7] = V[seq0+s8+j][d]
#pragma unroll
            for (int c = t; c < 512; c += 256) {
                const int d = c >> 3, s8 = (c & 7) * 8;
                const int seq = seq0 + s8;
                const int tile = seq >> 5;
                const int qd = (seq & 31) >> 3;
                const int nt = d >> 4, l16d = d & 15;
                const long dst = ((long)bh << 16) + tile * 2048 + nt * 512 + qd * 128 + l16d * 8;
                *(f16x8*)(vo + dst) = *(const f16x8*)&xh[d * XP + s8];
            }
        }
    }
}

// ------- Kernel 3: barrier-free flash attention, register-double-buffered K/V -------
// 32 q-rows per wave; K/V loads are lane-contiguous 1KB wave accesses (fragment-order layout).
// grid = (bh=96, qtile=8): same-bh blocks land on the same XCD (96 % 8 == 0).
__global__ __launch_bounds__(256) void k_attn(const f16* __restrict__ q,
                                              const f16* __restrict__ k,
                                              const f16* __restrict__ vt,
                                              float* __restrict__ out) {
    __shared__ __align__(16) f16 pl[4][32 * PLP];
    const int t = threadIdx.x;
    const int w = t >> 6, lane = t & 63, l16 = lane & 15, quad = lane >> 4;
    const int bh = blockIdx.x;
    const int q0 = blockIdx.y * 128 + w * 32; // this wave's 32 q-rows
    const long hb = (long)bh * SEQ;
    const f16* kp0 = k + ((long)bh << 16) + lane * 8;  // fragment-order base
    const f16* vp0 = vt + ((long)bh << 16) + lane * 8;

    f16x8 qf[2][2];
#pragma unroll
    for (int mt = 0; mt < 2; ++mt) {
        const f16* qp = q + (hb + q0 + mt * 16 + l16) * 64 + quad * 8;
        qf[mt][0] = *(const f16x8*)qp;
        qf[mt][1] = *(const f16x8*)(qp + 32);
    }
    f32x4 o[2][4];
    f32x4 ls[2];
#pragma unroll
    for (int mt = 0; mt < 2; ++mt) {
        ls[mt] = (f32x4){0.f, 0.f, 0.f, 0.f};
#pragma unroll
        for (int nt = 0; nt < 4; ++nt) o[mt][nt] = (f32x4){0.f, 0.f, 0.f, 0.f};
    }
    f16x8 one;
#pragma unroll
    for (int j = 0; j < 8; ++j) one[j] = (f16)1.0f;

#define LOADK(kt, kf)                                  \
    {                                                  \
        const f16* kp = kp0 + (kt) * 2048;             \
        kf[0] = *(const f16x8*)kp;                     \
        kf[1] = *(const f16x8*)(kp + 512);             \
        kf[2] = *(const f16x8*)(kp + 1024);            \
        kf[3] = *(const f16x8*)(kp + 1536);            \
    }
#define LOADV(kt, vf)                                  \
    {                                                  \
        const f16* vp = vp0 + (kt) * 2048;             \
        vf[0] = *(const f16x8*)vp;                     \
        vf[1] = *(const f16x8*)(vp + 512);             \
        vf[2] = *(const f16x8*)(vp + 1024);            \
        vf[3] = *(const f16x8*)(vp + 1536);            \
    }

    f16x8 ka[4], va[4], kb[4], vb[4];
    LOADK(0, ka);
    LOADV(0, va);

    auto body = [&](const f16x8* kf, const f16x8* vf) {
        f32x4 s[2][2];
        __builtin_amdgcn_s_setprio(1);
#pragma unroll
        for (int mt = 0; mt < 2; ++mt) {
            f32x4 a = {0.f, 0.f, 0.f, 0.f};
            a = __builtin_amdgcn_mfma_f32_16x16x32_f16(qf[mt][0], kf[0], a, 0, 0, 0);
            a = __builtin_amdgcn_mfma_f32_16x16x32_f16(qf[mt][1], kf[1], a, 0, 0, 0);
            s[mt][0] = a;
            f32x4 b = {0.f, 0.f, 0.f, 0.f};
            b = __builtin_amdgcn_mfma_f32_16x16x32_f16(qf[mt][0], kf[2], b, 0, 0, 0);
            b = __builtin_amdgcn_mfma_f32_16x16x32_f16(qf[mt][1], kf[3], b, 0, 0, 0);
            s[mt][1] = b;
        }
        __builtin_amdgcn_s_setprio(0);
        // fixed-offset exp (no max tracking); offset cancels in final normalization
#pragma unroll
        for (int mt = 0; mt < 2; ++mt)
#pragma unroll
            for (int ct = 0; ct < 2; ++ct)
#pragma unroll
                for (int rg = 0; rg < 4; ++rg) {
                    float p = __expf(s[mt][ct][rg] - 14.f);
                    pl[w][(mt * 16 + quad * 4 + rg) * PLP + ct * 16 + l16] = (f16)p;
                }
        f16x8 pf0 = *(const f16x8*)&pl[w][l16 * PLP + quad * 8];
        f16x8 pf1 = *(const f16x8*)&pl[w][(16 + l16) * PLP + quad * 8];
        __builtin_amdgcn_s_setprio(1);
        ls[0] = __builtin_amdgcn_mfma_f32_16x16x32_f16(pf0, one, ls[0], 0, 0, 0);
        ls[1] = __builtin_amdgcn_mfma_f32_16x16x32_f16(pf1, one, ls[1], 0, 0, 0);
#pragma unroll
        for (int nt = 0; nt < 4; ++nt) {
            o[0][nt] = __builtin_amdgcn_mfma_f32_16x16x32_f16(pf0, vf[nt], o[0][nt], 0, 0, 0);
            o[1][nt] = __builtin_amdgcn_mfma_f32_16x16x32_f16(pf1, vf[nt], o[1][nt], 0, 0, 0);
        }
        __builtin_amdgcn_s_setprio(0);
    };

    for (int kt = 0; kt < SEQ / 32; kt += 2) {
        LOADK(kt + 1, kb);
        LOADV(kt + 1, vb);
        body(ka, va);
        const int kn = (kt + 2 < SEQ / 32) ? kt + 2 : SEQ / 32 - 1; // clamped redundant load at end
        LOADK(kn, ka);
        LOADV(kn, va);
        body(kb, vb);
    }
#undef LOADK
#undef LOADV

    // epilogue: normalize by row-sum (ones-MFMA gave exact sums), then /sqrt(64)
#pragma unroll
    for (int mt = 0; mt < 2; ++mt) {
        float inv[4];
#pragma unroll
        for (int rg = 0; rg < 4; ++rg) inv[rg] = 1.f / (ls[mt][rg] * 8.0f);
#pragma unroll
        for (int nt = 0; nt < 4; ++nt) {
            float* op = out + (hb + q0 + mt * 16 + quad * 4) * 64 + nt * 16 + l16;
#pragma unroll
            for (int rg = 0; rg < 4; ++rg) op[(long)rg * 64] = o[mt][nt][rg] * inv[rg];
        }
    }
}

extern "C" void kernel_launch(void* const* d_in, const int* in_sizes, int n_in,
                              void* d_out, int out_size, void* d_ws, size_t ws_size,
                              hipStream_t stream) {
    const float* x = (const float*)d_in[0];
    const float* lw = (const float*)d_in[1];
    const float* lb = (const float*)d_in[2];
    const float* Wq = (const float*)d_in[3];
    const float* bq = (const float*)d_in[4];
    const float* Wk = (const float*)d_in[5];
    const float* bk = (const float*)d_in[6];
    const float* Wv = (const float*)d_in[7];
    const float* bv = (const float*)d_in[8];
    float* out = (float*)d_out;

    char* ws = (char*)d_ws;
    float* mu = (float*)ws;            // 8192 f32
    float* rs = (float*)(ws + 32768);  // 8192 f32
    f16* wfr = (f16*)(ws + 65536);     // 3*4096 f16 weight fragments
    f16* qo = (f16*)(ws + 98304);      // [row][64]
    f16* ko = qo + (long)NROWS * 64;   // fragment-interleaved per head
    f16* vo = ko + (long)NROWS * 64;   // fragment-interleaved per head

    k_lnstats<<<2048, 256, 0, stream>>>(x, Wq, Wk, Wv, mu, rs, wfr);
    k_qkv<<<NROWS / 64, 256, 0, stream>>>(x, lw, lb, wfr, bq, bk, bv, mu, rs, qo, ko, vo);
    k_attn<<<dim3(BS * HEADS, SEQ / 128), 256, 0, stream>>>(qo, ko, vo, out);
}

// Round 5
// 142.588 us; speedup vs baseline: 1.0768x; 1.0098x over previous
//
#include <hip/hip_runtime.h>

#define EMBED 768
#define HEADS 12
#define HD 64
#define SEQ 1024
#define BS 8
#define NROWS (BS * HEADS * SEQ) /* 98304 head-view rows, 64 wide */
#define XP 72                    /* padded LDS row (f16 elems) for qkv staging */
#define PLP 40                   /* P-tile stride: 80B rows -> 16B-aligned, quad conflicts 2-way (free) */

typedef _Float16 f16;
typedef f16 f16x4 __attribute__((ext_vector_type(4)));
typedef f16 f16x8 __attribute__((ext_vector_type(8)));
typedef float f32x4 __attribute__((ext_vector_type(4)));

// ---------------- Kernel 1: LayerNorm statistics + one-time W->f16 fragment conversion ----------------
// Blocks 0..2047: per-row mu/rstd. Blocks 0..2: additionally convert Wq/Wk/Wv (64x64 f32)
// into MFMA-B-fragment order f16: wf[m*4096 + (nt*2+half)*512 + lane*8 + j]
//   = W[nt*16 + (lane&15)][half*32 + (lane>>4)*8 + j]
__global__ __launch_bounds__(256) void k_lnstats(const float* __restrict__ x,
                                                 const float* __restrict__ Wq,
                                                 const float* __restrict__ Wk,
                                                 const float* __restrict__ Wv,
                                                 float* __restrict__ mu_out,
                                                 float* __restrict__ rs_out,
                                                 f16* __restrict__ wf) {
    const int w = threadIdx.x >> 6;
    const int lane = threadIdx.x & 63;
    const int row = blockIdx.x * 4 + w; // 0..8191
    const float4* xr = (const float4*)(x + (long)row * EMBED);
    float s = 0.f, sq = 0.f;
#pragma unroll
    for (int kk = 0; kk < 3; ++kk) {
        float4 v = xr[lane + kk * 64];
        s += v.x + v.y + v.z + v.w;
        sq += v.x * v.x + v.y * v.y + v.z * v.z + v.w * v.w;
    }
#pragma unroll
    for (int off = 32; off; off >>= 1) {
        s += __shfl_xor(s, off, 64);
        sq += __shfl_xor(sq, off, 64);
    }
    if (lane == 0) {
        float mu = s * (1.f / EMBED);
        float var = sq * (1.f / EMBED) - mu * mu;
        mu_out[row] = mu;
        rs_out[row] = rsqrtf(var + 1e-5f);
    }
    if (blockIdx.x < 3) {
        const float* W = (blockIdx.x == 0) ? Wq : (blockIdx.x == 1) ? Wk : Wv;
        f16* dst = wf + (long)blockIdx.x * 4096;
        const int t = threadIdx.x;
#pragma unroll
        for (int i = 0; i < 2; ++i) {
            const int o = t * 2 + i; // octet index 0..511
            const int nt = o >> 7, half = (o >> 6) & 1, lp = o & 63;
            const int qd = lp >> 4, l16 = lp & 15;
            const float* src = W + (nt * 16 + l16) * 64 + half * 32 + qd * 8;
            float4 v0 = *(const float4*)src, v1 = *(const float4*)(src + 4);
            f16x8 h = {(f16)v0.x, (f16)v0.y, (f16)v0.z, (f16)v0.w,
                       (f16)v1.x, (f16)v1.y, (f16)v1.z, (f16)v1.w};
            *(f16x8*)(dst + o * 8) = h;
        }
    }
}

// ------- Kernel 2: fused LN-apply + Q/K/V projection (weights pre-fragmented in wf) -------
// Q -> row-major [row][64].
// K,V -> MFMA-fragment-interleaved: per head, per 32-kv-row tile, 4 chunks of 512 f16.
// Stores iterate in DESTINATION-LINEAR order (each wave writes a contiguous 1KB span);
// the fragment permutation is applied on the LDS-read side instead (fixes 16-segment
// scattered global writes: 16B at 256B stride per lane).
__global__ __launch_bounds__(256) void k_qkv(
    const float* __restrict__ x, const float* __restrict__ lw, const float* __restrict__ lb,
    const f16* __restrict__ wf,
    const float* __restrict__ bq, const float* __restrict__ bk, const float* __restrict__ bv,
    const float* __restrict__ mu, const float* __restrict__ rs,
    f16* __restrict__ qo, f16* __restrict__ ko, f16* __restrict__ vo) {
    __shared__ __align__(16) f16 xh[64 * XP]; // input tile; reused as output staging
    const int t = threadIdx.x;
    const unsigned r0 = (unsigned)blockIdx.x * 64; // global head-view row base
    const int bh = (int)(r0 >> 10);
    const int seq0 = (int)(r0 & 1023);
    const int tile0 = seq0 >> 5; // first 32-kv tile this block covers (2 tiles total)

    // stage 64 head-view rows of LN(x) into LDS (fp16), b64 writes
    {
        const unsigned fb = r0 * 64u + (unsigned)t * 16u; // < 2^23, 32-bit div ok
        const unsigned xrow = fb / EMBED;
        const unsigned c0 = fb % EMBED;
        const float m_ = mu[xrow], s_ = rs[xrow];
        const int lrow = (t * 16) >> 6, lcol = (t * 16) & 63;
        f16* dst = &xh[lrow * XP + lcol];
        const float4* xp = (const float4*)(x + fb);
        const float4* wp = (const float4*)(lw + c0);
        const float4* bp = (const float4*)(lb + c0);
#pragma unroll
        for (int j = 0; j < 4; ++j) {
            float4 xv = xp[j], wv = wp[j], bv2 = bp[j];
            f16x4 h = {(f16)((xv.x - m_) * s_ * wv.x + bv2.x), (f16)((xv.y - m_) * s_ * wv.y + bv2.y),
                       (f16)((xv.z - m_) * s_ * wv.z + bv2.z), (f16)((xv.w - m_) * s_ * wv.w + bv2.w)};
            *(f16x4*)(dst + j * 4) = h;
        }
    }
    __syncthreads();

    const int lane = t & 63, w = t >> 6, l16 = lane & 15, quad = lane >> 4;
    // A fragments into registers (xh is free for reuse after the next barrier)
    f16x8 a0 = *(const f16x8*)&xh[(w * 16 + l16) * XP + quad * 8];
    f16x8 a1 = *(const f16x8*)&xh[(w * 16 + l16) * XP + 32 + quad * 8];
    const float* Bs[3] = {bq, bk, bv};

#pragma unroll
    for (int m = 0; m < 3; ++m) {
        // B-fragments straight from global (L1-hot 24KB working set), no LDS staging
        const f16* wfm = wf + (long)m * 4096 + lane * 8;
        f32x4 acc[4];
#pragma unroll
        for (int nt = 0; nt < 4; ++nt) {
            f16x8 b0 = *(const f16x8*)(wfm + (nt * 2 + 0) * 512);
            f16x8 b1 = *(const f16x8*)(wfm + (nt * 2 + 1) * 512);
            f32x4 a = {0.f, 0.f, 0.f, 0.f};
            a = __builtin_amdgcn_mfma_f32_16x16x32_f16(a0, b0, a, 0, 0, 0);
            a = __builtin_amdgcn_mfma_f32_16x16x32_f16(a1, b1, a, 0, 0, 0);
            const float bias = Bs[m][nt * 16 + l16];
#pragma unroll
            for (int rg = 0; rg < 4; ++rg) a[rg] += bias;
            acc[nt] = a;
        }

        __syncthreads(); // previous users of xh done
        if (m < 2) {
            // stage [row(seq-local)][col(d)] (scalar b16: 4 rows share a col)
#pragma unroll
            for (int nt = 0; nt < 4; ++nt)
#pragma unroll
                for (int rg = 0; rg < 4; ++rg)
                    xh[(w * 16 + quad * 4 + rg) * XP + nt * 16 + l16] = (f16)acc[nt][rg];
        } else {
            // stage transposed [col(d)][row(seq-local)] — rg contiguous -> b64
#pragma unroll
            for (int nt = 0; nt < 4; ++nt) {
                f16x4 h = {(f16)acc[nt][0], (f16)acc[nt][1], (f16)acc[nt][2], (f16)acc[nt][3]};
                *(f16x4*)&xh[(nt * 16 + l16) * XP + w * 16 + quad * 4] = h;
            }
        }
        __syncthreads();
        if (m == 0) {
            // Q: row-major (wave writes contiguous 1KB)
#pragma unroll
            for (int c = t; c < 512; c += 256) {
                const int row = c >> 3, c8 = (c & 7) * 8;
                *(f16x8*)(qo + ((long)r0 + row) * 64 + c8) = *(const f16x8*)&xh[row * XP + c8];
            }
        } else if (m == 1) {
            // K: destination-linear store; o=c*8 -> (tl,chunk,qd,l16s)
            //    src row = tl*32+(chunk>>1)*16+l16s, col = (chunk&1)*32+qd*8
            f16* kb = ko + ((long)bh << 16) + (long)tile0 * 2048;
#pragma unroll
            for (int c = t; c < 512; c += 256) {
                const int tl = c >> 8, chunk = (c >> 6) & 3, qd = (c >> 4) & 3, l16s = c & 15;
                const int row = tl * 32 + (chunk >> 1) * 16 + l16s;
                const int col = (chunk & 1) * 32 + qd * 8;
                *(f16x8*)(kb + (long)c * 8) = *(const f16x8*)&xh[row * XP + col];
            }
        } else {
            // V: destination-linear store; o=c*8 -> (tl,nt,qd,l16d)
            //    src = xh[(nt*16+l16d)][tl*32+qd*8] (transposed staging)
            f16* vb = vo + ((long)bh << 16) + (long)tile0 * 2048;
#pragma unroll
            for (int c = t; c < 512; c += 256) {
                const int tl = c >> 8, nt = (c >> 6) & 3, qd = (c >> 4) & 3, l16d = c & 15;
                *(f16x8*)(vb + (long)c * 8) = *(const f16x8*)&xh[(nt * 16 + l16d) * XP + tl * 32 + qd * 8];
            }
        }
    }
}

// ------- Kernel 3: barrier-free flash attention, register-double-buffered K/V -------
// 32 q-rows per wave; K/V loads are lane-contiguous 1KB wave accesses (fragment-order layout).
// grid = (bh=96, qtile=8): same-bh blocks land on the same XCD (96 % 8 == 0).
__global__ __launch_bounds__(256) void k_attn(const f16* __restrict__ q,
                                              const f16* __restrict__ k,
                                              const f16* __restrict__ vt,
                                              float* __restrict__ out) {
    __shared__ __align__(16) f16 pl[4][32 * PLP];
    const int t = threadIdx.x;
    const int w = t >> 6, lane = t & 63, l16 = lane & 15, quad = lane >> 4;
    const int bh = blockIdx.x;
    const int q0 = blockIdx.y * 128 + w * 32; // this wave's 32 q-rows
    const long hb = (long)bh * SEQ;
    const f16* kp0 = k + ((long)bh << 16) + lane * 8;  // fragment-order base
    const f16* vp0 = vt + ((long)bh << 16) + lane * 8;

    f16x8 qf[2][2];
#pragma unroll
    for (int mt = 0; mt < 2; ++mt) {
        const f16* qp = q + (hb + q0 + mt * 16 + l16) * 64 + quad * 8;
        qf[mt][0] = *(const f16x8*)qp;
        qf[mt][1] = *(const f16x8*)(qp + 32);
    }
    f32x4 o[2][4];
    f32x4 ls[2];
#pragma unroll
    for (int mt = 0; mt < 2; ++mt) {
        ls[mt] = (f32x4){0.f, 0.f, 0.f, 0.f};
#pragma unroll
        for (int nt = 0; nt < 4; ++nt) o[mt][nt] = (f32x4){0.f, 0.f, 0.f, 0.f};
    }
    f16x8 one;
#pragma unroll
    for (int j = 0; j < 8; ++j) one[j] = (f16)1.0f;

#define LOADK(kt, kf)                                  \
    {                                                  \
        const f16* kp = kp0 + (kt) * 2048;             \
        kf[0] = *(const f16x8*)kp;                     \
        kf[1] = *(const f16x8*)(kp + 512);             \
        kf[2] = *(const f16x8*)(kp + 1024);            \
        kf[3] = *(const f16x8*)(kp + 1536);            \
    }
#define LOADV(kt, vf)                                  \
    {                                                  \
        const f16* vp = vp0 + (kt) * 2048;             \
        vf[0] = *(const f16x8*)vp;                     \
        vf[1] = *(const f16x8*)(vp + 512);             \
        vf[2] = *(const f16x8*)(vp + 1024);            \
        vf[3] = *(const f16x8*)(vp + 1536);            \
    }

    f16x8 ka[4], va[4], kb[4], vb[4];
    LOADK(0, ka);
    LOADV(0, va);

    auto body = [&](const f16x8* kf, const f16x8* vf) {
        f32x4 s[2][2];
#pragma unroll
        for (int mt = 0; mt < 2; ++mt) {
            f32x4 a = {0.f, 0.f, 0.f, 0.f};
            a = __builtin_amdgcn_mfma_f32_16x16x32_f16(qf[mt][0], kf[0], a, 0, 0, 0);
            a = __builtin_amdgcn_mfma_f32_16x16x32_f16(qf[mt][1], kf[1], a, 0, 0, 0);
            s[mt][0] = a;
            f32x4 b = {0.f, 0.f, 0.f, 0.f};
            b = __builtin_amdgcn_mfma_f32_16x16x32_f16(qf[mt][0], kf[2], b, 0, 0, 0);
            b = __builtin_amdgcn_mfma_f32_16x16x32_f16(qf[mt][1], kf[3], b, 0, 0, 0);
            s[mt][1] = b;
        }
        // fixed-offset exp (no max tracking); offset cancels in final normalization
#pragma unroll
        for (int mt = 0; mt < 2; ++mt)
#pragma unroll
            for (int ct = 0; ct < 2; ++ct)
#pragma unroll
                for (int rg = 0; rg < 4; ++rg) {
                    float p = __expf(s[mt][ct][rg] - 14.f);
                    pl[w][(mt * 16 + quad * 4 + rg) * PLP + ct * 16 + l16] = (f16)p;
                }
        f16x8 pf0 = *(const f16x8*)&pl[w][l16 * PLP + quad * 8];
        f16x8 pf1 = *(const f16x8*)&pl[w][(16 + l16) * PLP + quad * 8];
        ls[0] = __builtin_amdgcn_mfma_f32_16x16x32_f16(pf0, one, ls[0], 0, 0, 0);
        ls[1] = __builtin_amdgcn_mfma_f32_16x16x32_f16(pf1, one, ls[1], 0, 0, 0);
#pragma unroll
        for (int nt = 0; nt < 4; ++nt) {
            o[0][nt] = __builtin_amdgcn_mfma_f32_16x16x32_f16(pf0, vf[nt], o[0][nt], 0, 0, 0);
            o[1][nt] = __builtin_amdgcn_mfma_f32_16x16x32_f16(pf1, vf[nt], o[1][nt], 0, 0, 0);
        }
    };

    for (int kt = 0; kt < SEQ / 32; kt += 2) {
        LOADK(kt + 1, kb);
        LOADV(kt + 1, vb);
        body(ka, va);
        const int kn = (kt + 2 < SEQ / 32) ? kt + 2 : SEQ / 32 - 1; // clamped redundant load at end
        LOADK(kn, ka);
        LOADV(kn, va);
        body(kb, vb);
    }
#undef LOADK
#undef LOADV

    // epilogue: normalize by row-sum (ones-MFMA gave exact sums), then /sqrt(64)
#pragma unroll
    for (int mt = 0; mt < 2; ++mt) {
        float inv[4];
#pragma unroll
        for (int rg = 0; rg < 4; ++rg) inv[rg] = 1.f / (ls[mt][rg] * 8.0f);
#pragma unroll
        for (int nt = 0; nt < 4; ++nt) {
            float* op = out + (hb + q0 + mt * 16 + quad * 4) * 64 + nt * 16 + l16;
#pragma unroll
            for (int rg = 0; rg < 4; ++rg) op[(long)rg * 64] = o[mt][nt][rg] * inv[rg];
        }
    }
}

extern "C" void kernel_launch(void* const* d_in, const int* in_sizes, int n_in,
                              void* d_out, int out_size, void* d_ws, size_t ws_size,
                              hipStream_t stream) {
    const float* x = (const float*)d_in[0];
    const float* lw = (const float*)d_in[1];
    const float* lb = (const float*)d_in[2];
    const float* Wq = (const float*)d_in[3];
    const float* bq = (const float*)d_in[4];
    const float* Wk = (const float*)d_in[5];
    const float* bk = (const float*)d_in[6];
    const float* Wv = (const float*)d_in[7];
    const float* bv = (const float*)d_in[8];
    float* out = (float*)d_out;

    char* ws = (char*)d_ws;
    float* mu = (float*)ws;            // 8192 f32
    float* rs = (float*)(ws + 32768);  // 8192 f32
    f16* wfr = (f16*)(ws + 65536);     // 3*4096 f16 weight fragments
    f16* qo = (f16*)(ws + 98304);      // [row][64]
    f16* ko = qo + (long)NROWS * 64;   // fragment-interleaved per head
    f16* vo = ko + (long)NROWS * 64;   // fragment-interleaved per head

    k_lnstats<<<2048, 256, 0, stream>>>(x, Wq, Wk, Wv, mu, rs, wfr);
    k_qkv<<<NROWS / 64, 256, 0, stream>>>(x, lw, lb, wfr, bq, bk, bv, mu, rs, qo, ko, vo);
    k_attn<<<dim3(BS * HEADS, SEQ / 128), 256, 0, stream>>>(qo, ko, vo, out);
}

// Round 7
// 139.587 us; speedup vs baseline: 1.0999x; 1.0215x over previous
//
#include <hip/hip_runtime.h>

#define EMBED 768
#define HEADS 12
#define HD 64
#define SEQ 1024
#define BS 8
#define NROWS (BS * HEADS * SEQ) /* 98304 head-view rows, 64 wide */
#define XP 72                    /* padded LDS row (f16 elems) for qkv staging */
#define PLP 40                   /* P-tile stride: 80B rows -> 16B-aligned, quad conflicts 2-way (free) */

typedef _Float16 f16;
typedef f16 f16x4 __attribute__((ext_vector_type(4)));
typedef f16 f16x8 __attribute__((ext_vector_type(8)));
typedef float f32x4 __attribute__((ext_vector_type(4)));

// ---------------- Kernel 1: LayerNorm statistics + one-time W->f16 fragment conversion ----------------
__global__ __launch_bounds__(256) void k_lnstats(const float* __restrict__ x,
                                                 const float* __restrict__ Wq,
                                                 const float* __restrict__ Wk,
                                                 const float* __restrict__ Wv,
                                                 float* __restrict__ mu_out,
                                                 float* __restrict__ rs_out,
                                                 f16* __restrict__ wf) {
    const int w = threadIdx.x >> 6;
    const int lane = threadIdx.x & 63;
    const int row = blockIdx.x * 4 + w; // 0..8191
    const float4* xr = (const float4*)(x + (long)row * EMBED);
    float s = 0.f, sq = 0.f;
#pragma unroll
    for (int kk = 0; kk < 3; ++kk) {
        float4 v = xr[lane + kk * 64];
        s += v.x + v.y + v.z + v.w;
        sq += v.x * v.x + v.y * v.y + v.z * v.z + v.w * v.w;
    }
#pragma unroll
    for (int off = 32; off; off >>= 1) {
        s += __shfl_xor(s, off, 64);
        sq += __shfl_xor(sq, off, 64);
    }
    if (lane == 0) {
        float mu = s * (1.f / EMBED);
        float var = sq * (1.f / EMBED) - mu * mu;
        mu_out[row] = mu;
        rs_out[row] = rsqrtf(var + 1e-5f);
    }
    if (blockIdx.x < 3) {
        const float* W = (blockIdx.x == 0) ? Wq : (blockIdx.x == 1) ? Wk : Wv;
        f16* dst = wf + (long)blockIdx.x * 4096;
        const int t = threadIdx.x;
#pragma unroll
        for (int i = 0; i < 2; ++i) {
            const int o = t * 2 + i; // octet index 0..511
            const int nt = o >> 7, half = (o >> 6) & 1, lp = o & 63;
            const int qd = lp >> 4, l16 = lp & 15;
            const float* src = W + (nt * 16 + l16) * 64 + half * 32 + qd * 8;
            float4 v0 = *(const float4*)src, v1 = *(const float4*)(src + 4);
            f16x8 h = {(f16)v0.x, (f16)v0.y, (f16)v0.z, (f16)v0.w,
                       (f16)v1.x, (f16)v1.y, (f16)v1.z, (f16)v1.w};
            *(f16x8*)(dst + o * 8) = h;
        }
    }
}

// ------- Kernel 2: fused LN-apply + Q/K/V projection, 128 head-rows per block -------
// Q -> row-major [row][64].
// K -> fragment-interleaved (unchanged layout).
// V -> fragment-interleaved with sigma row-permutation: position p in a 32-kv tile holds
//      V row r(p) = ((p&1)<<4)|(p>>1), matching attn's packed-pair P layout (sigma(k)=2(k&15)+(k>>4)).
__global__ __launch_bounds__(256) void k_qkv(
    const float* __restrict__ x, const float* __restrict__ lw, const float* __restrict__ lb,
    const f16* __restrict__ wf,
    const float* __restrict__ bq, const float* __restrict__ bk, const float* __restrict__ bv,
    const float* __restrict__ mu, const float* __restrict__ rs,
    f16* __restrict__ qo, f16* __restrict__ ko, f16* __restrict__ vo) {
    __shared__ __align__(16) f16 xh[2][64 * XP]; // input tiles; reused as output staging
    const int t = threadIdx.x;
    const unsigned r0 = (unsigned)blockIdx.x * 128; // global head-view row base (head-aligned: 128|1024)
    const int bh = (int)(r0 >> 10);
    const int seq0 = (int)(r0 & 1023);
    const int tile0 = seq0 >> 5; // first of 4 32-kv tiles this block covers

    // stage 2x64 head-view rows of LN(x) into LDS (fp16)
#pragma unroll
    for (int st = 0; st < 2; ++st) {
        const unsigned fb = (r0 + st * 64u) * 64u + (unsigned)t * 16u; // < 2^23
        const unsigned xrow = fb / EMBED;
        const unsigned c0 = fb % EMBED;
        const float m_ = mu[xrow], s_ = rs[xrow];
        const int lrow = (t * 16) >> 6, lcol = (t * 16) & 63;
        f16* dst = &xh[st][lrow * XP + lcol];
        const float4* xp = (const float4*)(x + fb);
        const float4* wp = (const float4*)(lw + c0);
        const float4* bp = (const float4*)(lb + c0);
#pragma unroll
        for (int j = 0; j < 4; ++j) {
            float4 xv = xp[j], wv = wp[j], bv2 = bp[j];
            f16x4 h = {(f16)((xv.x - m_) * s_ * wv.x + bv2.x), (f16)((xv.y - m_) * s_ * wv.y + bv2.y),
                       (f16)((xv.z - m_) * s_ * wv.z + bv2.z), (f16)((xv.w - m_) * s_ * wv.w + bv2.w)};
            *(f16x4*)(dst + j * 4) = h;
        }
    }
    __syncthreads();

    const int lane = t & 63, w = t >> 6, l16 = lane & 15, quad = lane >> 4;
    // A fragments into registers (xh free for reuse after the next barrier)
    f16x8 a[2][2];
#pragma unroll
    for (int st = 0; st < 2; ++st) {
        a[st][0] = *(const f16x8*)&xh[st][(w * 16 + l16) * XP + quad * 8];
        a[st][1] = *(const f16x8*)&xh[st][(w * 16 + l16) * XP + 32 + quad * 8];
    }
    const float* Bs[3] = {bq, bk, bv};

#pragma unroll
    for (int m = 0; m < 3; ++m) {
        // B-fragments straight from global (L1-hot 24KB working set)
        const f16* wfm = wf + (long)m * 4096 + lane * 8;
        f32x4 acc[2][4];
#pragma unroll
        for (int nt = 0; nt < 4; ++nt) {
            f16x8 b0 = *(const f16x8*)(wfm + (nt * 2 + 0) * 512);
            f16x8 b1 = *(const f16x8*)(wfm + (nt * 2 + 1) * 512);
            const float bias = Bs[m][nt * 16 + l16];
#pragma unroll
            for (int st = 0; st < 2; ++st) {
                f32x4 a_ = {0.f, 0.f, 0.f, 0.f};
                a_ = __builtin_amdgcn_mfma_f32_16x16x32_f16(a[st][0], b0, a_, 0, 0, 0);
                a_ = __builtin_amdgcn_mfma_f32_16x16x32_f16(a[st][1], b1, a_, 0, 0, 0);
#pragma unroll
                for (int rg = 0; rg < 4; ++rg) a_[rg] += bias;
                acc[st][nt] = a_;
            }
        }

        __syncthreads(); // previous users of xh done
        if (m < 2) {
            // stage [row(seq-local)][col(d)]
#pragma unroll
            for (int st = 0; st < 2; ++st)
#pragma unroll
                for (int nt = 0; nt < 4; ++nt)
#pragma unroll
                    for (int rg = 0; rg < 4; ++rg)
                        xh[st][(w * 16 + quad * 4 + rg) * XP + nt * 16 + l16] = (f16)acc[st][nt][rg];
        } else {
            // stage transposed [col(d)][row(seq-local)] — rg contiguous -> b64
#pragma unroll
            for (int st = 0; st < 2; ++st)
#pragma unroll
                for (int nt = 0; nt < 4; ++nt) {
                    f16x4 h = {(f16)acc[st][nt][0], (f16)acc[st][nt][1], (f16)acc[st][nt][2], (f16)acc[st][nt][3]};
                    *(f16x4*)&xh[st][(nt * 16 + l16) * XP + w * 16 + quad * 4] = h;
                }
        }
        __syncthreads();
        if (m == 0) {
            // Q: row-major (wave writes contiguous 1KB)
#pragma unroll
            for (int st = 0; st < 2; ++st)
#pragma unroll
                for (int c = t; c < 512; c += 256) {
                    const int row = c >> 3, c8 = (c & 7) * 8;
                    *(f16x8*)(qo + ((long)r0 + st * 64 + row) * 64 + c8) = *(const f16x8*)&xh[st][row * XP + c8];
                }
        } else if (m == 1) {
            // K: destination-linear store; o=c*8 -> (tl,chunk,qd,l16s)
#pragma unroll
            for (int st = 0; st < 2; ++st) {
                f16* kb = ko + ((long)bh << 16) + (long)(tile0 + st * 2) * 2048;
#pragma unroll
                for (int c = t; c < 512; c += 256) {
                    const int tl = c >> 8, chunk = (c >> 6) & 3, qd = (c >> 4) & 3, l16s = c & 15;
                    const int row = tl * 32 + (chunk >> 1) * 16 + l16s;
                    const int col = (chunk & 1) * 32 + qd * 8;
                    *(f16x8*)(kb + (long)c * 8) = *(const f16x8*)&xh[st][row * XP + col];
                }
            }
        } else {
            // V: destination-linear store with sigma interleave: position p holds V row
            //    r(p) = ((p&1)<<4)|(p>>1); octet (qd,j) -> rows {qd*4+j/2} (even j) / {16+qd*4+j/2} (odd j)
#pragma unroll
            for (int st = 0; st < 2; ++st) {
                f16* vb = vo + ((long)bh << 16) + (long)(tile0 + st * 2) * 2048;
#pragma unroll
                for (int c = t; c < 512; c += 256) {
                    const int tl = c >> 8, nt = (c >> 6) & 3, qd = (c >> 4) & 3, l16d = c & 15;
                    const f16* base = &xh[st][(nt * 16 + l16d) * XP + tl * 32 + qd * 4];
                    f16x4 lo = *(const f16x4*)base;
                    f16x4 hi = *(const f16x4*)(base + 16);
                    f16x8 o8 = {lo[0], hi[0], lo[1], hi[1], lo[2], hi[2], lo[3], hi[3]};
                    *(f16x8*)(vb + (long)c * 8) = o8;
                }
            }
        }
    }
}

// ------- Kernel 3: barrier-free flash attention, register-double-buffered K/V -------
// 32 q-rows per wave; K/V loads are lane-contiguous 1KB wave accesses (fragment-order layout).
// Softmax path: QK accumulator seeded with -14 (no subs); P written as packed f16 pairs
// (cvt_pkrtz + ds_write_b32) at sigma-permuted columns; V rows sigma-permuted to match.
// grid = (bh=96, qtile=8): same-bh blocks land on the same XCD (96 % 8 == 0).
__global__ __launch_bounds__(256) void k_attn(const f16* __restrict__ q,
                                              const f16* __restrict__ k,
                                              const f16* __restrict__ vt,
                                              float* __restrict__ out) {
    __shared__ __align__(16) f16 pl[4][32 * PLP];
    const int t = threadIdx.x;
    const int w = t >> 6, lane = t & 63, l16 = lane & 15, quad = lane >> 4;
    const int bh = blockIdx.x;
    const int q0 = blockIdx.y * 128 + w * 32; // this wave's 32 q-rows
    const long hb = (long)bh * SEQ;
    const f16* kp0 = k + ((long)bh << 16) + lane * 8;  // fragment-order base
    const f16* vp0 = vt + ((long)bh << 16) + lane * 8;

    f16x8 qf[2][2];
#pragma unroll
    for (int mt = 0; mt < 2; ++mt) {
        const f16* qp = q + (hb + q0 + mt * 16 + l16) * 64 + quad * 8;
        qf[mt][0] = *(const f16x8*)qp;
        qf[mt][1] = *(const f16x8*)(qp + 32);
    }
    f32x4 o[2][4];
    f32x4 ls[2];
#pragma unroll
    for (int mt = 0; mt < 2; ++mt) {
        ls[mt] = (f32x4){0.f, 0.f, 0.f, 0.f};
#pragma unroll
        for (int nt = 0; nt < 4; ++nt) o[mt][nt] = (f32x4){0.f, 0.f, 0.f, 0.f};
    }
    f16x8 one;
#pragma unroll
    for (int j = 0; j < 8; ++j) one[j] = (f16)1.0f;
    const f32x4 m14 = {-14.f, -14.f, -14.f, -14.f}; // exp offset folded into MFMA C-init

#define LOADK(kt, kf)                                  \
    {                                                  \
        const f16* kp = kp0 + (kt) * 2048;             \
        kf[0] = *(const f16x8*)kp;                     \
        kf[1] = *(const f16x8*)(kp + 512);             \
        kf[2] = *(const f16x8*)(kp + 1024);            \
        kf[3] = *(const f16x8*)(kp + 1536);            \
    }
#define LOADV(kt, vf)                                  \
    {                                                  \
        const f16* vp = vp0 + (kt) * 2048;             \
        vf[0] = *(const f16x8*)vp;                     \
        vf[1] = *(const f16x8*)(vp + 512);             \
        vf[2] = *(const f16x8*)(vp + 1024);            \
        vf[3] = *(const f16x8*)(vp + 1536);            \
    }

    f16x8 ka[4], va[4], kb[4], vb[4];
    LOADK(0, ka);
    LOADV(0, va);

    auto body = [&](const f16x8* kf, const f16x8* vf) {
        f32x4 s[2][2];
#pragma unroll
        for (int mt = 0; mt < 2; ++mt) {
            f32x4 a = m14;
            a = __builtin_amdgcn_mfma_f32_16x16x32_f16(qf[mt][0], kf[0], a, 0, 0, 0);
            a = __builtin_amdgcn_mfma_f32_16x16x32_f16(qf[mt][1], kf[1], a, 0, 0, 0);
            s[mt][0] = a;
            f32x4 b = m14;
            b = __builtin_amdgcn_mfma_f32_16x16x32_f16(qf[mt][0], kf[2], b, 0, 0, 0);
            b = __builtin_amdgcn_mfma_f32_16x16x32_f16(qf[mt][1], kf[3], b, 0, 0, 0);
            s[mt][1] = b;
        }
        // packed exp: pair (k-tile0, k-tile1) -> f16 pair at sigma-permuted column 2*l16
#pragma unroll
        for (int mt = 0; mt < 2; ++mt)
#pragma unroll
            for (int rg = 0; rg < 4; ++rg) {
                float e0 = __expf(s[mt][0][rg]);
                float e1 = __expf(s[mt][1][rg]);
                auto pk = __builtin_amdgcn_cvt_pkrtz(e0, e1); // __fp16 ext_vector(2)
                *(decltype(pk)*)&pl[w][(mt * 16 + quad * 4 + rg) * PLP + l16 * 2] = pk;
            }
        f16x8 pf0 = *(const f16x8*)&pl[w][l16 * PLP + quad * 8];
        f16x8 pf1 = *(const f16x8*)&pl[w][(16 + l16) * PLP + quad * 8];
        ls[0] = __builtin_amdgcn_mfma_f32_16x16x32_f16(pf0, one, ls[0], 0, 0, 0);
        ls[1] = __builtin_amdgcn_mfma_f32_16x16x32_f16(pf1, one, ls[1], 0, 0, 0);
#pragma unroll
        for (int nt = 0; nt < 4; ++nt) {
            o[0][nt] = __builtin_amdgcn_mfma_f32_16x16x32_f16(pf0, vf[nt], o[0][nt], 0, 0, 0);
            o[1][nt] = __builtin_amdgcn_mfma_f32_16x16x32_f16(pf1, vf[nt], o[1][nt], 0, 0, 0);
        }
    };

    for (int kt = 0; kt < SEQ / 32; kt += 2) {
        LOADK(kt + 1, kb);
        LOADV(kt + 1, vb);
        body(ka, va);
        const int kn = (kt + 2 < SEQ / 32) ? kt + 2 : SEQ / 32 - 1; // clamped redundant load at end
        LOADK(kn, ka);
        LOADV(kn, va);
        body(kb, vb);
    }
#undef LOADK
#undef LOADV

    // epilogue: normalize by row-sum (ones-MFMA gave exact sums), then /sqrt(64)
#pragma unroll
    for (int mt = 0; mt < 2; ++mt) {
        float inv[4];
#pragma unroll
        for (int rg = 0; rg < 4; ++rg) inv[rg] = 1.f / (ls[mt][rg] * 8.0f);
#pragma unroll
        for (int nt = 0; nt < 4; ++nt) {
            float* op = out + (hb + q0 + mt * 16 + quad * 4) * 64 + nt * 16 + l16;
#pragma unroll
            for (int rg = 0; rg < 4; ++rg) op[(long)rg * 64] = o[mt][nt][rg] * inv[rg];
        }
    }
}

extern "C" void kernel_launch(void* const* d_in, const int* in_sizes, int n_in,
                              void* d_out, int out_size, void* d_ws, size_t ws_size,
                              hipStream_t stream) {
    const float* x = (const float*)d_in[0];
    const float* lw = (const float*)d_in[1];
    const float* lb = (const float*)d_in[2];
    const float* Wq = (const float*)d_in[3];
    const float* bq = (const float*)d_in[4];
    const float* Wk = (const float*)d_in[5];
    const float* bk = (const float*)d_in[6];
    const float* Wv = (const float*)d_in[7];
    const float* bv = (const float*)d_in[8];
    float* out = (float*)d_out;

    char* ws = (char*)d_ws;
    float* mu = (float*)ws;            // 8192 f32
    float* rs = (float*)(ws + 32768);  // 8192 f32
    f16* wfr = (f16*)(ws + 65536);     // 3*4096 f16 weight fragments
    f16* qo = (f16*)(ws + 98304);      // [row][64]
    f16* ko = qo + (long)NROWS * 64;   // fragment-interleaved per head
    f16* vo = ko + (long)NROWS * 64;   // fragment-interleaved per head (sigma row order)

    k_lnstats<<<2048, 256, 0, stream>>>(x, Wq, Wk, Wv, mu, rs, wfr);
    k_qkv<<<NROWS / 128, 256, 0, stream>>>(x, lw, lb, wfr, bq, bk, bv, mu, rs, qo, ko, vo);
    k_attn<<<dim3(BS * HEADS, SEQ / 128), 256, 0, stream>>>(qo, ko, vo, out);
}

// Round 8
// 138.808 us; speedup vs baseline: 1.1061x; 1.0056x over previous
//
#include <hip/hip_runtime.h>

#define EMBED 768
#define HEADS 12
#define HD 64
#define SEQ 1024
#define BS 8
#define NROWS (BS * HEADS * SEQ) /* 98304 head-view rows, 64 wide */
#define XP 72                    /* padded LDS row (f16 elems) for qkv staging */
#define PLP 40                   /* P-tile stride: 80B rows -> 16B-aligned, quad conflicts 2-way (free) */

typedef _Float16 f16;
typedef f16 f16x4 __attribute__((ext_vector_type(4)));
typedef f16 f16x8 __attribute__((ext_vector_type(8)));
typedef float f32x4 __attribute__((ext_vector_type(4)));

// ---------------- Kernel 1: LayerNorm statistics + one-time W->f16 fragment conversion ----------------
__global__ __launch_bounds__(256) void k_lnstats(const float* __restrict__ x,
                                                 const float* __restrict__ Wq,
                                                 const float* __restrict__ Wk,
                                                 const float* __restrict__ Wv,
                                                 float* __restrict__ mu_out,
                                                 float* __restrict__ rs_out,
                                                 f16* __restrict__ wf) {
    const int w = threadIdx.x >> 6;
    const int lane = threadIdx.x & 63;
    const int row = blockIdx.x * 4 + w; // 0..8191
    const float4* xr = (const float4*)(x + (long)row * EMBED);
    float s = 0.f, sq = 0.f;
#pragma unroll
    for (int kk = 0; kk < 3; ++kk) {
        float4 v = xr[lane + kk * 64];
        s += v.x + v.y + v.z + v.w;
        sq += v.x * v.x + v.y * v.y + v.z * v.z + v.w * v.w;
    }
#pragma unroll
    for (int off = 32; off; off >>= 1) {
        s += __shfl_xor(s, off, 64);
        sq += __shfl_xor(sq, off, 64);
    }
    if (lane == 0) {
        float mu = s * (1.f / EMBED);
        float var = sq * (1.f / EMBED) - mu * mu;
        mu_out[row] = mu;
        rs_out[row] = rsqrtf(var + 1e-5f);
    }
    if (blockIdx.x < 3) {
        const float* W = (blockIdx.x == 0) ? Wq : (blockIdx.x == 1) ? Wk : Wv;
        f16* dst = wf + (long)blockIdx.x * 4096;
        const int t = threadIdx.x;
#pragma unroll
        for (int i = 0; i < 2; ++i) {
            const int o = t * 2 + i; // octet index 0..511
            const int nt = o >> 7, half = (o >> 6) & 1, lp = o & 63;
            const int qd = lp >> 4, l16 = lp & 15;
            const float* src = W + (nt * 16 + l16) * 64 + half * 32 + qd * 8;
            float4 v0 = *(const float4*)src, v1 = *(const float4*)(src + 4);
            f16x8 h = {(f16)v0.x, (f16)v0.y, (f16)v0.z, (f16)v0.w,
                       (f16)v1.x, (f16)v1.y, (f16)v1.z, (f16)v1.w};
            *(f16x8*)(dst + o * 8) = h;
        }
    }
}

// ------- Kernel 2: fused LN-apply + Q/K/V projection, 128 head-rows per block, ONE barrier -------
// Every wave's pre-store LDS traffic is confined to its own 16-row slice (x-staging rows t>>2,
// A-frag reads w*16+l16, Q-staging w*16+quad*4+rg -> all in [16w,16w+16)), and K/V staging values
// are thread-unique -> no cross-wave hazard until the linear store phase. Single __syncthreads()
// before stores; no mid-kernel vmcnt drains (stores fire once, drain at kernel end).
// Layouts (verified vs round-5 mapping): K chunk = (r16*2+cseg), V sigma row r(p)=((p&1)<<4)|(p>>1).
__global__ __launch_bounds__(256) void k_qkv(
    const float* __restrict__ x, const float* __restrict__ lw, const float* __restrict__ lb,
    const f16* __restrict__ wf,
    const float* __restrict__ bq, const float* __restrict__ bk, const float* __restrict__ bv,
    const float* __restrict__ mu, const float* __restrict__ rs,
    f16* __restrict__ qo, f16* __restrict__ ko, f16* __restrict__ vo) {
    __shared__ __align__(16) f16 xh[2][64 * XP]; // input tiles; reused as Q staging
    __shared__ __align__(16) f16 kb[2][4096];    // K fragment-layout staging (16KB)
    __shared__ __align__(16) f16 vb[2][4096];    // V fragment-layout staging (16KB)
    const int t = threadIdx.x;
    const unsigned r0 = (unsigned)blockIdx.x * 128; // head-aligned (128 | 1024)
    const int bh = (int)(r0 >> 10);
    const int seq0 = (int)(r0 & 1023);
    const int tile0 = seq0 >> 5; // first of 4 32-kv tiles this block covers

    // stage 2x64 head-view rows of LN(x) into LDS (fp16); wave-local row slice
#pragma unroll
    for (int st = 0; st < 2; ++st) {
        const unsigned fb = (r0 + st * 64u) * 64u + (unsigned)t * 16u; // < 2^23
        const unsigned xrow = fb / EMBED;
        const unsigned c0 = fb % EMBED;
        const float m_ = mu[xrow], s_ = rs[xrow];
        const int lrow = (t * 16) >> 6, lcol = (t * 16) & 63;
        f16* dst = &xh[st][lrow * XP + lcol];
        const float4* xp = (const float4*)(x + fb);
        const float4* wp = (const float4*)(lw + c0);
        const float4* bp = (const float4*)(lb + c0);
#pragma unroll
        for (int j = 0; j < 4; ++j) {
            float4 xv = xp[j], wv = wp[j], bv2 = bp[j];
            f16x4 h = {(f16)((xv.x - m_) * s_ * wv.x + bv2.x), (f16)((xv.y - m_) * s_ * wv.y + bv2.y),
                       (f16)((xv.z - m_) * s_ * wv.z + bv2.z), (f16)((xv.w - m_) * s_ * wv.w + bv2.w)};
            *(f16x4*)(dst + j * 4) = h;
        }
    }

    // NO barrier: A-frags read only this wave's own staged rows (in-wave lgkm ordering)
    const int lane = t & 63, w = t >> 6, l16 = lane & 15, quad = lane >> 4;
    f16x8 a[2][2];
#pragma unroll
    for (int st = 0; st < 2; ++st) {
        a[st][0] = *(const f16x8*)&xh[st][(w * 16 + l16) * XP + quad * 8];
        a[st][1] = *(const f16x8*)&xh[st][(w * 16 + l16) * XP + 32 + quad * 8];
    }
    const float* Bs[3] = {bq, bk, bv};

#pragma unroll
    for (int m = 0; m < 3; ++m) {
        const f16* wfm = wf + (long)m * 4096 + lane * 8; // B-frags, L1-hot 24KB
        f32x4 acc[2][4];
#pragma unroll
        for (int nt = 0; nt < 4; ++nt) {
            f16x8 b0 = *(const f16x8*)(wfm + (nt * 2 + 0) * 512);
            f16x8 b1 = *(const f16x8*)(wfm + (nt * 2 + 1) * 512);
            const float bias = Bs[m][nt * 16 + l16];
#pragma unroll
            for (int st = 0; st < 2; ++st) {
                f32x4 a_ = {0.f, 0.f, 0.f, 0.f};
                a_ = __builtin_amdgcn_mfma_f32_16x16x32_f16(a[st][0], b0, a_, 0, 0, 0);
                a_ = __builtin_amdgcn_mfma_f32_16x16x32_f16(a[st][1], b1, a_, 0, 0, 0);
#pragma unroll
                for (int rg = 0; rg < 4; ++rg) a_[rg] += bias;
                acc[st][nt] = a_;
            }
        }
        if (m == 0) {
            // Q staging into xh (own row slice; input already consumed into a[])
#pragma unroll
            for (int st = 0; st < 2; ++st)
#pragma unroll
                for (int nt = 0; nt < 4; ++nt)
#pragma unroll
                    for (int rg = 0; rg < 4; ++rg)
                        xh[st][(w * 16 + quad * 4 + rg) * XP + nt * 16 + l16] = (f16)acc[st][nt][rg];
        } else if (m == 1) {
            // K fragment-layout: off = (w>>1)*2048 + ((w&1)*2+(nt>>1))*512 + (((nt&1)<<1)|(l16>>3))*128
            //                        + (quad*4+rg)*8 + (l16&7)
#pragma unroll
            for (int st = 0; st < 2; ++st)
#pragma unroll
                for (int nt = 0; nt < 4; ++nt) {
                    const int base = (w >> 1) * 2048 + ((w & 1) * 2 + (nt >> 1)) * 512 +
                                     ((((nt & 1) << 1) | (l16 >> 3))) * 128 + (quad * 4) * 8 + (l16 & 7);
#pragma unroll
                    for (int rg = 0; rg < 4; ++rg)
                        kb[st][base + rg * 8] = (f16)acc[st][nt][rg];
                }
        } else {
            // V fragment-layout (sigma rows): off = (w>>1)*2048 + nt*512 + quad*128 + l16*8 + rg*2 + (w&1)
#pragma unroll
            for (int st = 0; st < 2; ++st)
#pragma unroll
                for (int nt = 0; nt < 4; ++nt) {
                    const int base = (w >> 1) * 2048 + nt * 512 + quad * 128 + l16 * 8 + (w & 1);
#pragma unroll
                    for (int rg = 0; rg < 4; ++rg)
                        vb[st][base + rg * 2] = (f16)acc[st][nt][rg];
                }
        }
    }

    __syncthreads(); // single barrier: all staging visible for cross-wave linear stores

    // Q: row-major, wave stores contiguous 1KB
#pragma unroll
    for (int st = 0; st < 2; ++st)
#pragma unroll
        for (int c = t; c < 512; c += 256) {
            const int row = c >> 3, c8 = (c & 7) * 8;
            *(f16x8*)(qo + ((long)r0 + st * 64 + row) * 64 + c8) = *(const f16x8*)&xh[st][row * XP + c8];
        }
    // K,V: fully linear 16KB block regions
    {
        f16* kg = ko + ((long)bh << 16) + (long)tile0 * 2048;
        f16* vg = vo + ((long)bh << 16) + (long)tile0 * 2048;
        const f16* kfl = &kb[0][0];
        const f16* vfl = &vb[0][0];
#pragma unroll
        for (int i = 0; i < 4; ++i) {
            const int o = (t + i * 256) * 8;
            *(f16x8*)(kg + o) = *(const f16x8*)(kfl + o);
            *(f16x8*)(vg + o) = *(const f16x8*)(vfl + o);
        }
    }
}

// ------- Kernel 3: barrier-free flash attention, register-double-buffered K/V (unchanged) -------
__global__ __launch_bounds__(256) void k_attn(const f16* __restrict__ q,
                                              const f16* __restrict__ k,
                                              const f16* __restrict__ vt,
                                              float* __restrict__ out) {
    __shared__ __align__(16) f16 pl[4][32 * PLP];
    const int t = threadIdx.x;
    const int w = t >> 6, lane = t & 63, l16 = lane & 15, quad = lane >> 4;
    const int bh = blockIdx.x;
    const int q0 = blockIdx.y * 128 + w * 32; // this wave's 32 q-rows
    const long hb = (long)bh * SEQ;
    const f16* kp0 = k + ((long)bh << 16) + lane * 8;  // fragment-order base
    const f16* vp0 = vt + ((long)bh << 16) + lane * 8;

    f16x8 qf[2][2];
#pragma unroll
    for (int mt = 0; mt < 2; ++mt) {
        const f16* qp = q + (hb + q0 + mt * 16 + l16) * 64 + quad * 8;
        qf[mt][0] = *(const f16x8*)qp;
        qf[mt][1] = *(const f16x8*)(qp + 32);
    }
    f32x4 o[2][4];
    f32x4 ls[2];
#pragma unroll
    for (int mt = 0; mt < 2; ++mt) {
        ls[mt] = (f32x4){0.f, 0.f, 0.f, 0.f};
#pragma unroll
        for (int nt = 0; nt < 4; ++nt) o[mt][nt] = (f32x4){0.f, 0.f, 0.f, 0.f};
    }
    f16x8 one;
#pragma unroll
    for (int j = 0; j < 8; ++j) one[j] = (f16)1.0f;
    const f32x4 m14 = {-14.f, -14.f, -14.f, -14.f}; // exp offset folded into MFMA C-init

#define LOADK(kt, kf)                                  \
    {                                                  \
        const f16* kp = kp0 + (kt) * 2048;             \
        kf[0] = *(const f16x8*)kp;                     \
        kf[1] = *(const f16x8*)(kp + 512);             \
        kf[2] = *(const f16x8*)(kp + 1024);            \
        kf[3] = *(const f16x8*)(kp + 1536);            \
    }
#define LOADV(kt, vf)                                  \
    {                                                  \
        const f16* vp = vp0 + (kt) * 2048;             \
        vf[0] = *(const f16x8*)vp;                     \
        vf[1] = *(const f16x8*)(vp + 512);             \
        vf[2] = *(const f16x8*)(vp + 1024);            \
        vf[3] = *(const f16x8*)(vp + 1536);            \
    }

    f16x8 ka[4], va[4], kb[4], vb[4];
    LOADK(0, ka);
    LOADV(0, va);

    auto body = [&](const f16x8* kf, const f16x8* vf) {
        f32x4 s[2][2];
#pragma unroll
        for (int mt = 0; mt < 2; ++mt) {
            f32x4 a = m14;
            a = __builtin_amdgcn_mfma_f32_16x16x32_f16(qf[mt][0], kf[0], a, 0, 0, 0);
            a = __builtin_amdgcn_mfma_f32_16x16x32_f16(qf[mt][1], kf[1], a, 0, 0, 0);
            s[mt][0] = a;
            f32x4 b = m14;
            b = __builtin_amdgcn_mfma_f32_16x16x32_f16(qf[mt][0], kf[2], b, 0, 0, 0);
            b = __builtin_amdgcn_mfma_f32_16x16x32_f16(qf[mt][1], kf[3], b, 0, 0, 0);
            s[mt][1] = b;
        }
        // packed exp: pair (k-tile0, k-tile1) -> f16 pair at sigma-permuted column 2*l16
#pragma unroll
        for (int mt = 0; mt < 2; ++mt)
#pragma unroll
            for (int rg = 0; rg < 4; ++rg) {
                float e0 = __expf(s[mt][0][rg]);
                float e1 = __expf(s[mt][1][rg]);
                auto pk = __builtin_amdgcn_cvt_pkrtz(e0, e1); // __fp16 ext_vector(2)
                *(decltype(pk)*)&pl[w][(mt * 16 + quad * 4 + rg) * PLP + l16 * 2] = pk;
            }
        f16x8 pf0 = *(const f16x8*)&pl[w][l16 * PLP + quad * 8];
        f16x8 pf1 = *(const f16x8*)&pl[w][(16 + l16) * PLP + quad * 8];
        ls[0] = __builtin_amdgcn_mfma_f32_16x16x32_f16(pf0, one, ls[0], 0, 0, 0);
        ls[1] = __builtin_amdgcn_mfma_f32_16x16x32_f16(pf1, one, ls[1], 0, 0, 0);
#pragma unroll
        for (int nt = 0; nt < 4; ++nt) {
            o[0][nt] = __builtin_amdgcn_mfma_f32_16x16x32_f16(pf0, vf[nt], o[0][nt], 0, 0, 0);
            o[1][nt] = __builtin_amdgcn_mfma_f32_16x16x32_f16(pf1, vf[nt], o[1][nt], 0, 0, 0);
        }
    };

    for (int kt = 0; kt < SEQ / 32; kt += 2) {
        LOADK(kt + 1, kb);
        LOADV(kt + 1, vb);
        body(ka, va);
        const int kn = (kt + 2 < SEQ / 32) ? kt + 2 : SEQ / 32 - 1; // clamped redundant load at end
        LOADK(kn, ka);
        LOADV(kn, va);
        body(kb, vb);
    }
#undef LOADK
#undef LOADV

    // epilogue: normalize by row-sum (ones-MFMA gave exact sums), then /sqrt(64)
#pragma unroll
    for (int mt = 0; mt < 2; ++mt) {
        float inv[4];
#pragma unroll
        for (int rg = 0; rg < 4; ++rg) inv[rg] = 1.f / (ls[mt][rg] * 8.0f);
#pragma unroll
        for (int nt = 0; nt < 4; ++nt) {
            float* op = out + (hb + q0 + mt * 16 + quad * 4) * 64 + nt * 16 + l16;
#pragma unroll
            for (int rg = 0; rg < 4; ++rg) op[(long)rg * 64] = o[mt][nt][rg] * inv[rg];
        }
    }
}

extern "C" void kernel_launch(void* const* d_in, const int* in_sizes, int n_in,
                              void* d_out, int out_size, void* d_ws, size_t ws_size,
                              hipStream_t stream) {
    const float* x = (const float*)d_in[0];
    const float* lw = (const float*)d_in[1];
    const float* lb = (const float*)d_in[2];
    const float* Wq = (const float*)d_in[3];
    const float* bq = (const float*)d_in[4];
    const float* Wk = (const float*)d_in[5];
    const float* bk = (const float*)d_in[6];
    const float* Wv = (const float*)d_in[7];
    const float* bv = (const float*)d_in[8];
    float* out = (float*)d_out;

    char* ws = (char*)d_ws;
    float* mu = (float*)ws;            // 8192 f32
    float* rs = (float*)(ws + 32768);  // 8192 f32
    f16* wfr = (f16*)(ws + 65536);     // 3*4096 f16 weight fragments
    f16* qo = (f16*)(ws + 98304);      // [row][64]
    f16* ko = qo + (long)NROWS * 64;   // fragment-interleaved per head
    f16* vo = ko + (long)NROWS * 64;   // fragment-interleaved per head (sigma row order)

    k_lnstats<<<2048, 256, 0, stream>>>(x, Wq, Wk, Wv, mu, rs, wfr);
    k_qkv<<<NROWS / 128, 256, 0, stream>>>(x, lw, lb, wfr, bq, bk, bv, mu, rs, qo, ko, vo);
    k_attn<<<dim3(BS * HEADS, SEQ / 128), 256, 0, stream>>>(qo, ko, vo, out);
}